// Round 10
// baseline (122.418 us; speedup 1.0000x reference)
//
#include <hip/hip_runtime.h>

// Chamfer distance, B=16, N=M=4096, 2-D fp32 points, prefix-length masks.
// d_out: [fwd 16*4096][bwd 16*4096] fp32.
//
// R16 = R14 (best, 79.3us) + REP=4 instrumentation on the j-scan.
// MEASUREMENT ROUND (results bit-identical; min is idempotent).
//  - R15 post-mortem: single-writer full-scan blocks = 89.0us (>=80 null);
//    R14 structure stays. R7's books finally close as LDS-issue-bound at
//    NQ=1 (18cy LDS vs 6cy VALU per pair) -- but R14's main (48 VALU per
//    2 LDS reads) still measures ~2-4x over its issue model, and our
//    kernels have NEVER appeared in top-5 counters (fills hold all slots).
//  - REP=4 on the j-loop: (1) Delta/3 = exact scan time, isolating scan
//    from staging+lookup+atomics+gap; (2) main's duration exceeds the
//    40us fills -> surfaces in top-5 WITH VALUBusy/Occupancy/LDS_CONFLICT.
//    asm volatile memory clobber between passes defeats CSE/DCE (the
//    compiler must reload LDS and recompute; rule #17).
//  - Pre-committed reads: Delta 40-55us -> scan dominates; its VALUBusy
//    >60% => VALU-bound (R17: cut FLOPs / drop precision -- threshold is
//    3.2e-2, we sit at 2e-3); VALUBusy<30% + low occ => tail imbalance
//    (R17: finer chunks); high LDS_BANK_CONFLICT => layout. Delta 9-15us
//    -> scan innocent, overhead is staging/lookup/atomics/launch (R17
//    attacks those).
//  - Everything else byte-identical to R14: single compute dispatch +
//    0x7F memset init (out_size is ELEMENT count -> x4 bytes), atomicMin
//    on uint bits (min commutes with sqrt; nonneg f32 bits uint-monotone),
//    pc0 atomicMin(0) padded tail, spare-block sentinels for Lp==0 rows,
//    query-skip KA in {4,8,12,16}, no fences.

#define REP 4
typedef float f2 __attribute__((ext_vector_type(2)));

template<int KA>
__device__ __forceinline__ void scan_queries(
    const float* __restrict__ Qrow,          // row base of query cloud
    const float4* __restrict__ sxy, const f2* __restrict__ sn,
    unsigned* __restrict__ orow_u, int tid)
{
    // KA*64 queries per wave; 4 state VGPRs per query (KA=16 -> ~90 total).
    float mx[KA], my[KA], s2[KA], best[KA];
    #pragma unroll
    for (int k = 0; k < KA; ++k) {
        const float2 q = ((const float2*)Qrow)[tid + k * 256];
        mx[k] = -2.f * q.x;
        my[k] = -2.f * q.y;
        s2[k] = fmaf(q.x, q.x, q.y * q.y);
        best[k] = 3.0e38f;
    }

    // INSTRUMENTATION: repeat the scan REP times. Pass 2..REP recompute
    // identical values; min is idempotent -> results unchanged. The
    // memory clobber forces real LDS reloads + recompute each pass.
    for (int rep = 0; rep < REP; ++rep) {
        #pragma unroll 4
        for (int j = 0; j < 64; ++j) {
            const float4 xy = sxy[j];
            const f2 xp = f2{xy.x, xy.y};
            const f2 yp = f2{xy.z, xy.w};
            const f2 np = sn[j];
            #pragma unroll
            for (int k = 0; k < KA; ++k) {
                f2 v = xp * mx[k] + np;       // pk_fma: n - 2qx*tx
                v = yp * my[k] + v;           // pk_fma: n - 2q.t
                best[k] = fminf(best[k], fminf(v.x, v.y));  // v_min3_f32
            }
        }
        asm volatile("" ::: "memory");        // defeat CSE/DCE across passes
    }

    // Final value per query from this block; global combine by atomicMin
    // on the uint bit pattern (monotone for nonneg floats). Fire-and-forget.
    #pragma unroll
    for (int k = 0; k < KA; ++k) {
        const float d = sqrtf(fmaxf(best[k] + s2[k], 0.f));
        atomicMin(orow_u + tid + k * 256, __float_as_uint(d));
    }
}

__global__ __launch_bounds__(256, 2) void chamfer_main(
    const float* __restrict__ src, const float* __restrict__ tgt,
    const int* __restrict__ slen, const int* __restrict__ tlen,
    float* __restrict__ out)
{
    __shared__ float4 sh_xy[64];   // {x0,x1,y0,y1} per point-pair
    __shared__ f2     sh_n[64];    // {|t0|^2, |t1|^2}

    const int g   = blockIdx.x;
    const int tid = threadIdx.x;

    // Compacted work lookup: g -> (row, pc). Uniform SALU.
    int row = -1, pc = 0, Lp = 0, acc = 0;
    #pragma unroll
    for (int rr = 0; rr < 32; ++rr) {
        const int L = (rr < 16) ? tlen[rr] : slen[rr - 16];  // search-side length
        const int n = (L + 127) >> 7;                        // active 128-pt chunks
        if (row < 0 && g < acc + n) { row = rr; pc = g - acc; Lp = L; }
        acc += n;
    }

    if (row < 0) {
        // Spare block: cleanup duty for rows with NO compute blocks
        // (Lp == 0): min over empty set = BIG -> sqrt(1e10) for q < Lq,
        // 0 for padded queries. Atomic-only (order-independent).
        const int cr = g - acc;                  // acc == total active units
        if (cr < 32) {
            const int dirc = cr >> 4, bc = cr & 15;
            const int Lpc = dirc ? slen[bc] : tlen[bc];
            if (Lpc == 0) {
                const int Lqc = dirc ? tlen[bc] : slen[bc];
                unsigned* op = (unsigned*)(out + cr * 4096);
                const unsigned sent = __float_as_uint(sqrtf(1e10f));
                #pragma unroll
                for (int k = 0; k < 16; ++k) {
                    const int q = tid + k * 256;
                    atomicMin(op + q, (q < Lqc) ? sent : 0u);
                }
            }
        }
        return;
    }
    const int dir = row >> 4, b = row & 15;

    const int Lq = dir ? tlen[b] : slen[b];      // query-side valid length
    unsigned* orow_u = (unsigned*)(out + row * 4096);

    // pc==0 forces the padded-query tail to 0 via atomicMin(0): any
    // interleaving with dead-value atomics ends at 0 (uint-min).
    if (pc == 0) {
        #pragma unroll
        for (int k = 0; k < 16; ++k) {
            const int q = tid + k * 256;
            if (q >= Lq) atomicMin(orow_u + q, 0u);
        }
    }

    const int KACT = (Lq + 255) >> 8;            // 0..16 active query slices
    if (KACT == 0) return;                       // uniform: no valid queries

    const float* Q = dir ? tgt : src;
    const float* P = dir ? src : tgt;

    // Stage 128 points (64 pairs), pair-packed; poison n for idx >= Lp.
    if (tid < 64) {
        const int base = pc * 128 + tid * 2;
        const float4 pp = ((const float4*)P)[(b * 4096 + base) >> 1];  // {x0,y0,x1,y1}
        const float n0 = (base + 0 < Lp) ? fmaf(pp.x, pp.x, pp.y * pp.y) : 1e30f;
        const float n1 = (base + 1 < Lp) ? fmaf(pp.z, pp.z, pp.w * pp.w) : 1e30f;
        sh_xy[tid] = make_float4(pp.x, pp.z, pp.y, pp.w);    // {x0,x1,y0,y1}
        sh_n[tid]  = f2{n0, n1};
    }
    __syncthreads();

    const float* Qrow = Q + b * 8192;            // row base (float2 elems)

    // Uniform dispatch on rounded-up active query slices. Queries in
    // [Lq, KA*256) get atomicMin'd with dead values but are forced to 0
    // by pc0's atomicMin(0) (order-independent).
    switch ((KACT + 3) >> 2) {
        case 1:  scan_queries< 4>(Qrow, sh_xy, sh_n, orow_u, tid); break;
        case 2:  scan_queries< 8>(Qrow, sh_xy, sh_n, orow_u, tid); break;
        case 3:  scan_queries<12>(Qrow, sh_xy, sh_n, orow_u, tid); break;
        default: scan_queries<16>(Qrow, sh_xy, sh_n, orow_u, tid); break;
    }
}

extern "C" void kernel_launch(void* const* d_in, const int* in_sizes, int n_in,
                              void* d_out, int out_size, void* d_ws, size_t ws_size,
                              hipStream_t stream) {
    const float* src = (const float*)d_in[0];   // [16,4096,2] f32
    const float* tgt = (const float*)d_in[1];   // [16,4096,2] f32
    const int* slen  = (const int*)d_in[2];     // [16] i32
    const int* tlen  = (const int*)d_in[3];     // [16] i32
    (void)d_ws; (void)ws_size;                  // workspace unused (no partials)

    // Init out to 0x7F7F7F7F = 3.39e38f (> any candidate). out_size is the
    // ELEMENT count -> bytes = x4 (R12/R13 bug). 131072 elems -> 524288 B.
    hipMemsetAsync(d_out, 0x7F, (size_t)out_size * sizeof(float), stream);
    chamfer_main<<<1024, 256, 0, stream>>>(src, tgt, slen, tlen, (float*)d_out);
}

// Round 11
// 90.943 us; speedup vs baseline: 1.3461x; 1.3461x over previous
//
#include <hip/hip_runtime.h>

// Chamfer distance, B=16, N=M=4096, 2-D fp32 points, prefix-length masks.
// d_out: [fwd 16*4096][bwd 16*4096] fp32.
//
// R17 = R14 skeleton, 256-pt chunks / 512-thr blocks / interleaved dispatch.
//  - R16 instrumentation (REP=4; first counters ever for our kernel):
//    scan = 14.4us/pass (Delta/3), main(REP=4) = 73.2us, VALUBusy 41%,
//    Occ 12.5%, LDS conflicts 0 -> main(REP=1) ~= 30us = scan 14.4 +
//    atomics ~13 (vs R10's plain-store main ~17us via R11 A/B) + staging ~3.
//    Scan runs ~2.4x over its VALU-busy model (low SCLK, uncontrollable)
//    with ~40% VALU idle (KA imbalance + tail).
//  - Change 1 (atomics x0.5): 256-pt chunks, 512 threads. Per-row chunks
//    halve -> total atomicMin ops ~1.3M -> ~0.7M, fan-in 32 -> 16.
//    Active blocks ~272 x 8 waves -> ~16 waves/CU unchanged.
//  - Change 2 (balance): non-compacted grid 32 rows x 16 slots,
//    row = g & 31 -> consecutive blocks hit different rows, mixing KA
//    durations per CU; kills the 32-iter compaction lookup. Inactive
//    slots exit immediately.
//  - Unchanged: single compute dispatch + 0x7F memset init (out_size is
//    ELEMENT count -> x4 bytes), atomicMin on uint bits (min commutes with
//    sqrt; nonneg f32 bits uint-monotone), pc0 zeroes padded tail via
//    atomicMin(0), Lp==0 rows sentinel'd by their pc0 slot, query-skip
//    KA in {2,4,6,8} (x512 thr), 2 v_pk_fma_f32 + v_min3_f32 per pair per
//    query, full f32 (absmax ~2e-3), no fences.
//  - Pre-committed read: <=74us confirms atomic-cost theory (R18: chunk=512
//    or grid/ring-search); >=78us -> atomic theory wrong, R18 goes
//    algorithmic (2D cell grid + expanding rings, ~50x scan cut).

typedef float f2 __attribute__((ext_vector_type(2)));

template<int KA>
__device__ __forceinline__ void scan_queries(
    const float* __restrict__ Qrow,          // row base of query cloud
    const float4* __restrict__ sxy, const f2* __restrict__ sn,
    unsigned* __restrict__ orow_u, int tid)
{
    // KA queries per thread (tid + k*512); 4 state VGPRs per query.
    float mx[KA], my[KA], s2[KA], best[KA];
    #pragma unroll
    for (int k = 0; k < KA; ++k) {
        const float2 q = ((const float2*)Qrow)[tid + k * 512];
        mx[k] = -2.f * q.x;
        my[k] = -2.f * q.y;
        s2[k] = fmaf(q.x, q.x, q.y * q.y);
        best[k] = 3.0e38f;
    }

    // Per point-pair per query: 2 v_pk_fma_f32 (scalar op_sel broadcast)
    // + 1 v_min3_f32; 2 broadcast LDS reads amortized over KA queries.
    #pragma unroll 4
    for (int j = 0; j < 128; ++j) {
        const float4 xy = sxy[j];
        const f2 xp = f2{xy.x, xy.y};
        const f2 yp = f2{xy.z, xy.w};
        const f2 np = sn[j];
        #pragma unroll
        for (int k = 0; k < KA; ++k) {
            f2 v = xp * mx[k] + np;       // pk_fma: n - 2qx*tx
            v = yp * my[k] + v;           // pk_fma: n - 2q.t
            best[k] = fminf(best[k], fminf(v.x, v.y));  // v_min3_f32
        }
    }

    // Final value per query from this block; global combine by atomicMin
    // on the uint bit pattern (monotone for nonneg floats). Fire-and-forget.
    #pragma unroll
    for (int k = 0; k < KA; ++k) {
        const float d = sqrtf(fmaxf(best[k] + s2[k], 0.f));
        atomicMin(orow_u + tid + k * 512, __float_as_uint(d));
    }
}

__global__ __launch_bounds__(512, 2) void chamfer_main(
    const float* __restrict__ src, const float* __restrict__ tgt,
    const int* __restrict__ slen, const int* __restrict__ tlen,
    float* __restrict__ out)
{
    __shared__ float4 sh_xy[128];  // {x0,x1,y0,y1} per point-pair
    __shared__ f2     sh_n[128];   // {|t0|^2, |t1|^2}

    const int g   = blockIdx.x;    // 512 = 16 chunk-slots x 32 rows
    const int tid = threadIdx.x;
    const int row = g & 31;        // interleave rows across consecutive blocks
    const int pc  = g >> 5;        // 256-pt chunk slot, 0..15
    const int dir = row >> 4, b = row & 15;

    const int Lq = dir ? tlen[b] : slen[b];      // query-side valid length
    const int Lp = dir ? slen[b] : tlen[b];      // search-side valid length
    unsigned* orow_u = (unsigned*)(out + row * 4096);

    if (Lp == 0) {
        // No valid search points: pc0 writes ref semantics for the whole
        // row: sqrt(1e10) for q < Lq (min over empty set = BIG), 0 beyond.
        // Atomic-only (order-independent vs nothing else -- sole writer).
        if (pc == 0) {
            const unsigned sent = __float_as_uint(sqrtf(1e10f));
            #pragma unroll
            for (int k = 0; k < 8; ++k) {
                const int q = tid + k * 512;
                atomicMin(orow_u + q, (q < Lq) ? sent : 0u);
            }
        }
        return;
    }
    if (pc * 256 >= Lp) return;                  // inactive chunk slot

    // pc==0 forces the padded-query tail to 0 via atomicMin(0): any
    // interleaving with dead-value atomics ends at 0 (uint-min).
    if (pc == 0) {
        #pragma unroll
        for (int k = 0; k < 8; ++k) {
            const int q = tid + k * 512;
            if (q >= Lq) atomicMin(orow_u + q, 0u);
        }
    }

    const int KACT = (Lq + 511) >> 9;            // 0..8 active query slices
    if (KACT == 0) return;                       // uniform: no valid queries

    const float* Q = dir ? tgt : src;
    const float* P = dir ? src : tgt;

    // Stage 256 points (128 pairs), pair-packed; poison n for idx >= Lp.
    if (tid < 128) {
        const int base = pc * 256 + tid * 2;
        const float4 pp = ((const float4*)P)[(b * 4096 + base) >> 1];  // {x0,y0,x1,y1}
        const float n0 = (base + 0 < Lp) ? fmaf(pp.x, pp.x, pp.y * pp.y) : 1e30f;
        const float n1 = (base + 1 < Lp) ? fmaf(pp.z, pp.z, pp.w * pp.w) : 1e30f;
        sh_xy[tid] = make_float4(pp.x, pp.z, pp.y, pp.w);    // {x0,x1,y0,y1}
        sh_n[tid]  = f2{n0, n1};
    }
    __syncthreads();

    const float* Qrow = Q + b * 8192;            // row base (float2 elems)

    // Uniform dispatch on rounded-up active query slices. Queries in
    // [Lq, KA*512) get atomicMin'd with dead values but are forced to 0
    // by pc0's atomicMin(0) (order-independent).
    switch ((KACT + 1) >> 1) {
        case 1:  scan_queries<2>(Qrow, sh_xy, sh_n, orow_u, tid); break;
        case 2:  scan_queries<4>(Qrow, sh_xy, sh_n, orow_u, tid); break;
        case 3:  scan_queries<6>(Qrow, sh_xy, sh_n, orow_u, tid); break;
        default: scan_queries<8>(Qrow, sh_xy, sh_n, orow_u, tid); break;
    }
}

extern "C" void kernel_launch(void* const* d_in, const int* in_sizes, int n_in,
                              void* d_out, int out_size, void* d_ws, size_t ws_size,
                              hipStream_t stream) {
    const float* src = (const float*)d_in[0];   // [16,4096,2] f32
    const float* tgt = (const float*)d_in[1];   // [16,4096,2] f32
    const int* slen  = (const int*)d_in[2];     // [16] i32
    const int* tlen  = (const int*)d_in[3];     // [16] i32
    (void)d_ws; (void)ws_size;                  // workspace unused

    // Init out to 0x7F7F7F7F = 3.39e38f (> any candidate). out_size is the
    // ELEMENT count -> bytes = x4. 131072 elems -> 524288 bytes.
    hipMemsetAsync(d_out, 0x7F, (size_t)out_size * sizeof(float), stream);
    chamfer_main<<<512, 512, 0, stream>>>(src, tgt, slen, tlen, (float*)d_out);
}

// Round 12
// 78.901 us; speedup vs baseline: 1.5515x; 1.1526x over previous
//
#include <hip/hip_runtime.h>

// Chamfer distance, B=16, N=M=4096, 2-D fp32 points, prefix-length masks.
// d_out: [fwd 16*4096][bwd 16*4096] fp32.
//
// R18 = R14 skeleton (best, 79.3us) + exact-KACT + stale-safe cond-atomic.
//  - R17 post-mortem (90.9): confounded round -- 512-thr blocks + slotted
//    dispatch regressed (both 512-thr rounds, R8/R17, lost big: 6/8 waves
//    idle at the staging barrier). Atomic theory NOT falsified. Reverted
//    to the proven 1024x256 compacted skeleton; R14 components unchanged.
//  - R16 budget for main (~30us): scan 14.4 + atomics ~13 + staging ~3.
//  - Cut 1, exact KACT in 1..16 (was rounded to {4,8,12,16}): kills up to
//    3 dead 256-query slices per block (~18% of scan AND atomic work;
//    E[KACT] 8.5 vs E[rounded] 10.5).
//  - Cut 2, conditional atomic: read out[idx] (plain load, possibly stale)
//    and skip the atomicMin when our candidate >= it. STALE-SAFE: stored
//    values only DECREASE over time, so any stale read >= true current;
//    if candidate >= stale >= current, the atomic could not improve the
//    result -- skipping is correct under any interleaving, no coherence
//    assumption. With fan-in 32, most RMWs become cached loads. Worst
//    case (reads pinned at init in local L2) = R14 + ~1-2us of loads.
//  - Unchanged from R14: single compute dispatch + 0x7F memset init
//    (out_size is ELEMENT count -> x4 bytes), atomicMin on uint bits (min
//    commutes with sqrt; nonneg f32 bits uint-monotone), pc0 atomicMin(0)
//    padded tail, spare-block sentinels for Lp==0 rows, 64-pair chunks,
//    2 v_pk_fma_f32 + v_min3_f32 per pair per query, full f32
//    (absmax ~2e-3), no fences (R3 lesson).
//  - Pre-committed read: <=74 both cuts real; 75-79 exact-KACT only
//    (conditional null, keep); >=80 conditional backfired -> revert it.

typedef float f2 __attribute__((ext_vector_type(2)));

template<int KA>
__device__ __forceinline__ void scan_queries(
    const float* __restrict__ Qrow,          // row base of query cloud
    const float4* __restrict__ sxy, const f2* __restrict__ sn,
    unsigned* __restrict__ orow_u, int tid)
{
    // KA*64 queries per wave; 4 state VGPRs per query (KA=16 -> ~90 total).
    float mx[KA], my[KA], s2[KA], best[KA];
    #pragma unroll
    for (int k = 0; k < KA; ++k) {
        const float2 q = ((const float2*)Qrow)[tid + k * 256];
        mx[k] = -2.f * q.x;
        my[k] = -2.f * q.y;
        s2[k] = fmaf(q.x, q.x, q.y * q.y);
        best[k] = 3.0e38f;
    }

    // Per point-pair per query: 2 v_pk_fma_f32 (scalar op_sel broadcast)
    // + 1 v_min3_f32; 2 broadcast LDS reads amortized over KA queries.
    #pragma unroll 4
    for (int j = 0; j < 64; ++j) {
        const float4 xy = sxy[j];
        const f2 xp = f2{xy.x, xy.y};
        const f2 yp = f2{xy.z, xy.w};
        const f2 np = sn[j];
        #pragma unroll
        for (int k = 0; k < KA; ++k) {
            f2 v = xp * mx[k] + np;       // pk_fma: n - 2qx*tx
            v = yp * my[k] + v;           // pk_fma: n - 2q.t
            best[k] = fminf(best[k], fminf(v.x, v.y));  // v_min3_f32
        }
    }

    // Final value per query; combine across blocks by atomicMin on the
    // uint bit pattern (monotone for nonneg floats). Conditional: skip
    // when a (stale-safe) read shows we cannot improve (values only
    // decrease -> stale >= current; candidate >= stale => useless RMW).
    unsigned cur[KA];
    #pragma unroll
    for (int k = 0; k < KA; ++k)
        cur[k] = orow_u[tid + k * 256];          // bulk-issued plain loads
    #pragma unroll
    for (int k = 0; k < KA; ++k) {
        const float d = sqrtf(fmaxf(best[k] + s2[k], 0.f));
        const unsigned bits = __float_as_uint(d);
        if (bits < cur[k])
            atomicMin(orow_u + tid + k * 256, bits);
    }
}

__global__ __launch_bounds__(256, 2) void chamfer_main(
    const float* __restrict__ src, const float* __restrict__ tgt,
    const int* __restrict__ slen, const int* __restrict__ tlen,
    float* __restrict__ out)
{
    __shared__ float4 sh_xy[64];   // {x0,x1,y0,y1} per point-pair
    __shared__ f2     sh_n[64];    // {|t0|^2, |t1|^2}

    const int g   = blockIdx.x;
    const int tid = threadIdx.x;

    // Compacted work lookup: g -> (row, pc). Uniform SALU.
    int row = -1, pc = 0, Lp = 0, acc = 0;
    #pragma unroll
    for (int rr = 0; rr < 32; ++rr) {
        const int L = (rr < 16) ? tlen[rr] : slen[rr - 16];  // search-side length
        const int n = (L + 127) >> 7;                        // active 128-pt chunks
        if (row < 0 && g < acc + n) { row = rr; pc = g - acc; Lp = L; }
        acc += n;
    }

    if (row < 0) {
        // Spare block: cleanup duty for rows with NO compute blocks
        // (Lp == 0): min over empty set = BIG -> sqrt(1e10) for q < Lq,
        // 0 for padded queries. Atomic-only (order-independent).
        const int cr = g - acc;                  // acc == total active units
        if (cr < 32) {
            const int dirc = cr >> 4, bc = cr & 15;
            const int Lpc = dirc ? slen[bc] : tlen[bc];
            if (Lpc == 0) {
                const int Lqc = dirc ? tlen[bc] : slen[bc];
                unsigned* op = (unsigned*)(out + cr * 4096);
                const unsigned sent = __float_as_uint(sqrtf(1e10f));
                #pragma unroll
                for (int k = 0; k < 16; ++k) {
                    const int q = tid + k * 256;
                    atomicMin(op + q, (q < Lqc) ? sent : 0u);
                }
            }
        }
        return;
    }
    const int dir = row >> 4, b = row & 15;

    const int Lq = dir ? tlen[b] : slen[b];      // query-side valid length
    unsigned* orow_u = (unsigned*)(out + row * 4096);

    // pc==0 forces the padded-query tail to 0 via atomicMin(0): any
    // interleaving with dead-value atomics ends at 0 (uint-min).
    if (pc == 0) {
        #pragma unroll
        for (int k = 0; k < 16; ++k) {
            const int q = tid + k * 256;
            if (q >= Lq) atomicMin(orow_u + q, 0u);
        }
    }

    const int KACT = (Lq + 255) >> 8;            // 0..16 active query slices
    if (KACT == 0) return;                       // uniform: no valid queries

    const float* Q = dir ? tgt : src;
    const float* P = dir ? src : tgt;

    // Stage 128 points (64 pairs), pair-packed; poison n for idx >= Lp.
    if (tid < 64) {
        const int base = pc * 128 + tid * 2;
        const float4 pp = ((const float4*)P)[(b * 4096 + base) >> 1];  // {x0,y0,x1,y1}
        const float n0 = (base + 0 < Lp) ? fmaf(pp.x, pp.x, pp.y * pp.y) : 1e30f;
        const float n1 = (base + 1 < Lp) ? fmaf(pp.z, pp.z, pp.w * pp.w) : 1e30f;
        sh_xy[tid] = make_float4(pp.x, pp.z, pp.y, pp.w);    // {x0,x1,y0,y1}
        sh_n[tid]  = f2{n0, n1};
    }
    __syncthreads();

    const float* Qrow = Q + b * 8192;            // row base (float2 elems)

    // EXACT active-slice dispatch (1..16): no dead query slices (was
    // rounded to {4,8,12,16} -> up to 3 x 256 wasted queries per block).
    switch (KACT) {
        case 1:  scan_queries< 1>(Qrow, sh_xy, sh_n, orow_u, tid); break;
        case 2:  scan_queries< 2>(Qrow, sh_xy, sh_n, orow_u, tid); break;
        case 3:  scan_queries< 3>(Qrow, sh_xy, sh_n, orow_u, tid); break;
        case 4:  scan_queries< 4>(Qrow, sh_xy, sh_n, orow_u, tid); break;
        case 5:  scan_queries< 5>(Qrow, sh_xy, sh_n, orow_u, tid); break;
        case 6:  scan_queries< 6>(Qrow, sh_xy, sh_n, orow_u, tid); break;
        case 7:  scan_queries< 7>(Qrow, sh_xy, sh_n, orow_u, tid); break;
        case 8:  scan_queries< 8>(Qrow, sh_xy, sh_n, orow_u, tid); break;
        case 9:  scan_queries< 9>(Qrow, sh_xy, sh_n, orow_u, tid); break;
        case 10: scan_queries<10>(Qrow, sh_xy, sh_n, orow_u, tid); break;
        case 11: scan_queries<11>(Qrow, sh_xy, sh_n, orow_u, tid); break;
        case 12: scan_queries<12>(Qrow, sh_xy, sh_n, orow_u, tid); break;
        case 13: scan_queries<13>(Qrow, sh_xy, sh_n, orow_u, tid); break;
        case 14: scan_queries<14>(Qrow, sh_xy, sh_n, orow_u, tid); break;
        case 15: scan_queries<15>(Qrow, sh_xy, sh_n, orow_u, tid); break;
        default: scan_queries<16>(Qrow, sh_xy, sh_n, orow_u, tid); break;
    }
}

extern "C" void kernel_launch(void* const* d_in, const int* in_sizes, int n_in,
                              void* d_out, int out_size, void* d_ws, size_t ws_size,
                              hipStream_t stream) {
    const float* src = (const float*)d_in[0];   // [16,4096,2] f32
    const float* tgt = (const float*)d_in[1];   // [16,4096,2] f32
    const int* slen  = (const int*)d_in[2];     // [16] i32
    const int* tlen  = (const int*)d_in[3];     // [16] i32
    (void)d_ws; (void)ws_size;                  // workspace unused

    // Init out to 0x7F7F7F7F = 3.39e38f (> any candidate). out_size is the
    // ELEMENT count -> bytes = x4. 131072 elems -> 524288 bytes.
    hipMemsetAsync(d_out, 0x7F, (size_t)out_size * sizeof(float), stream);
    chamfer_main<<<1024, 256, 0, stream>>>(src, tgt, slen, tlen, (float*)d_out);
}

// Round 13
// 78.392 us; speedup vs baseline: 1.5616x; 1.0065x over previous
//
#include <hip/hip_runtime.h>

// Chamfer distance, B=16, N=M=4096, 2-D fp32 points, prefix-length masks.
// d_out: [fwd 16*4096][bwd 16*4096] fp32.
//
// R19: query-split blocks -- flatten the critical path.
//  - Model fix (explains ALL nulls R9/R18): kernel duration = LONGEST
//    block, not total work. R16's 14.4us/scan-pass == one KA=16 block's
//    serial scan at observed issue rate; balanced floor is ~3-6us. Work
//    cuts (R9 45%, R18 exact-KACT) never shortened the longest block.
//  - Split: block = (row, chunk pc, query-group qg), KA <= 4 slices
//    (1024 queries) per block. Heavy rows (KACT up to 16) spread over 4x
//    more blocks; durations near-uniform. Atomic count UNCHANGED (same
//    (chunk,slice) coverage). Staging redone per qg -> L2-hit, cheap.
//    pc-major unit order keeps same-chunk blocks adjacent (L2 locality).
//  - launch_bounds(256,4): 4 blocks/CU resident (low VGPR), more overlap.
//  - Grid 4096 = worst-case sum of ceil(Lp/128) x max(ceil(KACT/4),1);
//    surplus blocks: first 32 spares handle Lp==0 rows (sentinel
//    sqrt(1e10)/0), rest exit after the SALU lookup.
//  - Carried from R14/R18 (all proven): 0x7F memset init (out_size is
//    ELEMENT count -> x4 bytes), atomic-only out writes (min commutes
//    with sqrt; nonneg f32 bits uint-monotone), pc0&qg0 tail-zero via
//    atomicMin(0), stale-safe conditional atomicMin, exact KA templates,
//    2 v_pk_fma_f32 + v_min3_f32 per pair per query, full f32
//    (absmax ~2e-3), no fences (R3 lesson).
//  - Pre-committed read: <=73 confirms critical-path model; 74-78 partial
//    (new floor = staging/drain); >=79 null -> fixed-overhead floor,
//    write the roofline case.

typedef float f2 __attribute__((ext_vector_type(2)));

template<int KA>
__device__ __forceinline__ void scan_queries(
    const float* __restrict__ Qrow,          // row base of query cloud
    const float4* __restrict__ sxy, const f2* __restrict__ sn,
    unsigned* __restrict__ orow_u, int tid, int q0)  // q0 = qg*1024
{
    // KA queries per thread (q0 + tid + k*256); 4 state VGPRs per query.
    float mx[KA], my[KA], s2[KA], best[KA];
    #pragma unroll
    for (int k = 0; k < KA; ++k) {
        const float2 q = ((const float2*)Qrow)[q0 + tid + k * 256];
        mx[k] = -2.f * q.x;
        my[k] = -2.f * q.y;
        s2[k] = fmaf(q.x, q.x, q.y * q.y);
        best[k] = 3.0e38f;
    }

    // Per point-pair per query: 2 v_pk_fma_f32 (scalar op_sel broadcast)
    // + 1 v_min3_f32; 2 broadcast LDS reads amortized over KA queries.
    #pragma unroll 4
    for (int j = 0; j < 64; ++j) {
        const float4 xy = sxy[j];
        const f2 xp = f2{xy.x, xy.y};
        const f2 yp = f2{xy.z, xy.w};
        const f2 np = sn[j];
        #pragma unroll
        for (int k = 0; k < KA; ++k) {
            f2 v = xp * mx[k] + np;       // pk_fma: n - 2qx*tx
            v = yp * my[k] + v;           // pk_fma: n - 2q.t
            best[k] = fminf(best[k], fminf(v.x, v.y));  // v_min3_f32
        }
    }

    // Stale-safe conditional atomicMin (R18): values only decrease, so a
    // stale read >= current; candidate >= stale => RMW cannot improve.
    unsigned cur[KA];
    #pragma unroll
    for (int k = 0; k < KA; ++k)
        cur[k] = orow_u[q0 + tid + k * 256];
    #pragma unroll
    for (int k = 0; k < KA; ++k) {
        const float d = sqrtf(fmaxf(best[k] + s2[k], 0.f));
        const unsigned bits = __float_as_uint(d);
        if (bits < cur[k])
            atomicMin(orow_u + q0 + tid + k * 256, bits);
    }
}

__global__ __launch_bounds__(256, 4) void chamfer_main(
    const float* __restrict__ src, const float* __restrict__ tgt,
    const int* __restrict__ slen, const int* __restrict__ tlen,
    float* __restrict__ out)
{
    __shared__ float4 sh_xy[64];   // {x0,x1,y0,y1} per point-pair
    __shared__ f2     sh_n[64];    // {|t0|^2, |t1|^2}

    const int g   = blockIdx.x;
    const int tid = threadIdx.x;

    // Compacted lookup: g -> (row, pc, qg). Uniform SALU.
    int row = -1, pc = 0, qg = 0, Lp = 0, Lq = 0, acc = 0;
    #pragma unroll
    for (int rr = 0; rr < 32; ++rr) {
        const int Ls  = (rr < 16) ? tlen[rr] : slen[rr - 16];  // search len
        const int Lqq = (rr < 16) ? slen[rr] : tlen[rr - 16];  // query len
        const int nch  = (Ls + 127) >> 7;                      // 128-pt chunks
        const int kact = (Lqq + 255) >> 8;                     // 256-q slices
        int nqg = (kact + 3) >> 2;                             // 4-slice groups
        if (nqg == 0) nqg = 1;                                 // keep pc0/qg0
        const int units = nch * nqg;                           // 0 iff Ls==0
        if (row < 0 && g < acc + units) {
            row = rr; const int u = g - acc;
            pc = u / nqg; qg = u - pc * nqg;                   // pc-major
            Lp = Ls; Lq = Lqq;
        }
        acc += units;
    }

    if (row < 0) {
        // Spare block: rows with NO compute units (Lp == 0): min over
        // empty set = BIG -> sqrt(1e10) for q < Lq, 0 beyond. Atomic-only.
        const int cr = g - acc;                  // acc == total active units
        if (cr < 32) {
            const int dirc = cr >> 4, bc = cr & 15;
            const int Lpc = dirc ? slen[bc] : tlen[bc];
            if (Lpc == 0) {
                const int Lqc = dirc ? tlen[bc] : slen[bc];
                unsigned* op = (unsigned*)(out + cr * 4096);
                const unsigned sent = __float_as_uint(sqrtf(1e10f));
                #pragma unroll
                for (int k = 0; k < 16; ++k) {
                    const int q = tid + k * 256;
                    atomicMin(op + q, (q < Lqc) ? sent : 0u);
                }
            }
        }
        return;
    }
    const int dir = row >> 4, b = row & 15;
    unsigned* orow_u = (unsigned*)(out + row * 4096);

    // One block per row (pc==0, qg==0) forces the padded-query tail to 0
    // via atomicMin(0): order-independent vs dead-value atomics. Covers
    // the whole row when Lq == 0.
    if (pc == 0 && qg == 0) {
        #pragma unroll
        for (int k = 0; k < 16; ++k) {
            const int q = tid + k * 256;
            if (q >= Lq) atomicMin(orow_u + q, 0u);
        }
    }

    const int KACT = (Lq + 255) >> 8;
    const int KB = min(4, KACT - qg * 4);        // this block's slices
    if (KB <= 0) return;                         // Lq==0 row (tail done)

    const float* Q = dir ? tgt : src;
    const float* P = dir ? src : tgt;

    // Stage 128 points (64 pairs), pair-packed; poison n for idx >= Lp.
    if (tid < 64) {
        const int base = pc * 128 + tid * 2;
        const float4 pp = ((const float4*)P)[(b * 4096 + base) >> 1];  // {x0,y0,x1,y1}
        const float n0 = (base + 0 < Lp) ? fmaf(pp.x, pp.x, pp.y * pp.y) : 1e30f;
        const float n1 = (base + 1 < Lp) ? fmaf(pp.z, pp.z, pp.w * pp.w) : 1e30f;
        sh_xy[tid] = make_float4(pp.x, pp.z, pp.y, pp.w);    // {x0,x1,y0,y1}
        sh_n[tid]  = f2{n0, n1};
    }
    __syncthreads();

    const float* Qrow = Q + b * 8192;            // row base (float2 elems)
    const int q0 = qg * 1024;                    // first query of this group

    switch (KB) {                                // exact slice count 1..4
        case 1:  scan_queries<1>(Qrow, sh_xy, sh_n, orow_u, tid, q0); break;
        case 2:  scan_queries<2>(Qrow, sh_xy, sh_n, orow_u, tid, q0); break;
        case 3:  scan_queries<3>(Qrow, sh_xy, sh_n, orow_u, tid, q0); break;
        default: scan_queries<4>(Qrow, sh_xy, sh_n, orow_u, tid, q0); break;
    }
}

extern "C" void kernel_launch(void* const* d_in, const int* in_sizes, int n_in,
                              void* d_out, int out_size, void* d_ws, size_t ws_size,
                              hipStream_t stream) {
    const float* src = (const float*)d_in[0];   // [16,4096,2] f32
    const float* tgt = (const float*)d_in[1];   // [16,4096,2] f32
    const int* slen  = (const int*)d_in[2];     // [16] i32
    const int* tlen  = (const int*)d_in[3];     // [16] i32
    (void)d_ws; (void)ws_size;                  // workspace unused

    // Init out to 0x7F7F7F7F = 3.39e38f (> any candidate). out_size is the
    // ELEMENT count -> bytes = x4. 131072 elems -> 524288 bytes.
    hipMemsetAsync(d_out, 0x7F, (size_t)out_size * sizeof(float), stream);
    // Worst-case units = 32 rows x 32 chunks x 4 qgroups = 4096.
    chamfer_main<<<4096, 256, 0, stream>>>(src, tgt, slen, tlen, (float*)d_out);
}